// Round 2
// baseline (838.434 us; speedup 1.0000x reference)
//
#include <hip/hip_runtime.h>
#include <stdint.h>

#define BATCH 64
#define IMH 512
#define IMW 512
#define NCH 3
#define NPIX 4096            // 64*64
#define FLAT 12288           // 3*4096
#define MAXN 196
#define KNB 6
#define NTOT (BATCH*MAXN)    // 12544
#define ETOT (NTOT*KNB)      // 75264

// out layout (float32 words), flat concat in reference return order:
// nodes_out  [0, 62720)
// edge_index row0 (src) [62720, 137984), row1 (dst) [137984, 213248)
// edge_feats [213248, 439040)
// batch_idx  [439040, 451584)
// node_valid [451584, 464128)
// edge_valid [464128, 539392)
#define OFF_NODES 0
#define OFF_SRC   62720
#define OFF_DST   137984
#define OFF_EF    213248
#define OFF_BI    439040
#define OFF_NV    451584
#define OFF_EV    464128

// ---------------- kernel 1: crop (bilinear, fp32 exact) + gray + 3 DoG convs ----
__global__ void k_crop_conv(const float* __restrict__ img,
                            const float* __restrict__ w1,
                            const float* __restrict__ w2,
                            const float* __restrict__ w3,
                            float* __restrict__ resp)
{
#pragma clang fp contract(off)
    int b = blockIdx.x;
    int tid = threadIdx.x;
    __shared__ float gray[64][64];
    __shared__ float wk1[9], wk2[25], wk3[81];
    if (tid < 9)  wk1[tid] = w1[tid];
    if (tid < 25) wk2[tid] = w2[tid];
    if (tid < 81) wk3[tid] = w3[tid];
    __syncthreads();

    const float* ib = img + (size_t)b * NCH * IMH * IMW;
    for (int p = tid; p < NPIX; p += blockDim.x) {
        int y = p >> 6, x = p & 63;
        float bx = ((float)x + 0.5f) / 32.0f - 1.0f;
        float gx = bx * 0.03125f;
        float px = (gx + 1.0f) * 512.0f / 2.0f - 0.5f;
        float by = ((float)y + 0.5f) / 32.0f - 1.0f;
        float gy = by * 0.03125f;
        float py = (gy + 1.0f) * 512.0f / 2.0f - 0.5f;
        int ix0 = (int)floorf(px); float fx = px - (float)ix0;
        int iy0 = (int)floorf(py); float fy = py - (float)iy0;
        // all sample points are interior (px in [247.6, 263.4]) -> v0=v1=1
        float wx0 = 1.0f - fx, wx1 = fx;
        float wy0 = 1.0f - fy, wy1 = fy;
        float s[3];
        for (int c = 0; c < 3; c++) {
            const float* cb = ib + (size_t)c * IMH * IMW;
            float a00 = cb[iy0 * IMW + ix0];
            float a01 = cb[iy0 * IMW + ix0 + 1];
            float a10 = cb[(iy0 + 1) * IMW + ix0];
            float a11 = cb[(iy0 + 1) * IMW + ix0 + 1];
            float t0 = a00 * wx0 + a01 * wx1;   // x-gather first (ref order)
            float t1 = a10 * wx0 + a11 * wx1;
            s[c] = t0 * wy0 + t1 * wy1;         // then y-gather
        }
        gray[y][x] = ((s[0] + s[1]) + s[2]) / 3.0f;   // mean over channels
    }
    __syncthreads();

    for (int p = tid; p < NPIX; p += blockDim.x) {
        int y = p >> 6, x = p & 63;
        double a1 = 0.0, a2 = 0.0, a3 = 0.0;
        for (int ky = 0; ky < 3; ky++) {
            int yy = y + ky - 1; if (yy < 0 || yy >= 64) continue;
            for (int kx = 0; kx < 3; kx++) {
                int xx = x + kx - 1; if (xx < 0 || xx >= 64) continue;
                a1 += (double)gray[yy][xx] * (double)wk1[ky * 3 + kx];
            }
        }
        for (int ky = 0; ky < 5; ky++) {
            int yy = y + ky - 2; if (yy < 0 || yy >= 64) continue;
            for (int kx = 0; kx < 5; kx++) {
                int xx = x + kx - 2; if (xx < 0 || xx >= 64) continue;
                a2 += (double)gray[yy][xx] * (double)wk2[ky * 5 + kx];
            }
        }
        for (int ky = 0; ky < 9; ky++) {
            int yy = y + ky - 4; if (yy < 0 || yy >= 64) continue;
            for (int kx = 0; kx < 9; kx++) {
                int xx = x + kx - 4; if (xx < 0 || xx >= 64) continue;
                a3 += (double)gray[yy][xx] * (double)wk3[ky * 9 + kx];
            }
        }
        size_t base = (size_t)b * FLAT;
        resp[base + p]            = (float)a1;
        resp[base + NPIX + p]     = (float)a2;
        resp[base + 2 * NPIX + p] = (float)a3;
    }
}

// ---------------- kernel 2: stable top-196 per batch (val desc, idx asc) --------
__global__ void k_topk(const float* __restrict__ resp,
                       float* __restrict__ topv,
                       int* __restrict__ topi)
{
    int b = blockIdx.x;
    int tid = threadIdx.x;
    __shared__ float sc[FLAT];          // 48 KiB
    __shared__ float rv[256];
    __shared__ int   ri[256];

    const float* rb = resp + (size_t)b * FLAT;
    for (int j = tid; j < FLAT; j += 256) {
        float v = rb[j];
        float m = fabsf(v);
        sc[j] = (m > 0.1f) ? m : -1.0f;
    }
    __syncthreads();

    for (int it = 0; it < MAXN; it++) {
        float bv = -__builtin_inff();
        int   bi = 0x7FFFFFFF;
        for (int j = tid; j < FLAT; j += 256) {
            float v = sc[j];
            if (v > bv) { bv = v; bi = j; }   // j ascending -> first max kept
        }
        rv[tid] = bv; ri[tid] = bi;
        __syncthreads();
        for (int off = 128; off >= 1; off >>= 1) {
            if (tid < off) {
                float ov = rv[tid + off]; int oi = ri[tid + off];
                if (ov > rv[tid] || (ov == rv[tid] && oi < ri[tid])) {
                    rv[tid] = ov; ri[tid] = oi;
                }
            }
            __syncthreads();
        }
        if (tid == 0) {
            topv[b * MAXN + it] = rv[0];
            topi[b * MAXN + it] = ri[0];
            sc[ri[0]] = -3.0e38f;            // below any real score (>= -1)
        }
        __syncthreads();
    }
}

// ---------------- kernel 3: nodes + 6-NN + edges, one block per batch ----------
__global__ void k_edges(const float* __restrict__ resp,
                        const float* __restrict__ topv,
                        const int* __restrict__ topi,
                        float* __restrict__ out)
{
#pragma clang fp contract(off)
    int b = blockIdx.x;
    int tid = threadIdx.x;
    __shared__ float cx[MAXN], cy[MAXN];
    __shared__ int   vld[MAXN];

    float* o_nodes = out + OFF_NODES;
    float* o_src   = out + OFF_SRC;
    float* o_dst   = out + OFF_DST;
    float* o_ef    = out + OFF_EF;
    float* o_bi    = out + OFF_BI;
    float* o_nv    = out + OFF_NV;
    float* o_ev    = out + OFF_EV;

    if (tid < MAXN) {
        float v  = topv[b * MAXN + tid];
        int   idx = topi[b * MAXN + tid];
        bool  val = v > 0.1f;
        int c   = idx >> 12;
        int rem = idx & 4095;
        int yi  = rem >> 6;
        int xi  = rem & 63;
        float xc = (float)xi / 63.0f * 2.0f - 1.0f;
        float yc = (float)yi / 63.0f * 2.0f - 1.0f;
        float x2 = xc * xc, y2 = yc * yc;
        float ecc = sqrtf(x2 + y2);
        float rvv = resp[(size_t)b * FLAT + idx];
        float pol = (rvv > 0.0f) ? 1.0f : ((rvv < 0.0f) ? -1.0f : 0.0f);
        float m = val ? 1.0f : 0.0f;
        size_t n = (size_t)b * MAXN + tid;
        o_nodes[n * 5 + 0] = xc * m;
        o_nodes[n * 5 + 1] = yc * m;
        o_nodes[n * 5 + 2] = pol * m;
        o_nodes[n * 5 + 3] = (float)c * m;
        o_nodes[n * 5 + 4] = ecc * m;
        o_nv[n] = m;
        o_bi[n] = (float)b;
        cx[tid] = xc * m;   // coords taken AFTER validity zeroing (ref semantics)
        cy[tid] = yc * m;
        vld[tid] = val ? 1 : 0;
    }
    __syncthreads();

    if (tid < MAXN) {
        int i = tid;
        float bd[KNB]; int bj[KNB];
#pragma unroll
        for (int k = 0; k < KNB; k++) { bd[k] = 3.0e38f; bj[k] = 0; }
        float cxi = cx[i], cyi = cy[i];
        int vi = vld[i];
        for (int j = 0; j < MAXN; j++) {
            float dx = cxi - cx[j];
            float dy = cyi - cy[j];
            float sx = dx * dx;
            float sy = dy * dy;
            float d2 = sx + sy;
            float dist = (d2 > 0.0f) ? sqrtf(d2) : 0.0f;
            bool ok = vi && vld[j] && (i != j);
            float dm = ok ? dist : 1.0e9f;
            if (dm < bd[KNB - 1]) {           // strict: equal dist keeps earlier j
                int p = KNB - 1;
                while (p > 0 && dm < bd[p - 1]) {
                    bd[p] = bd[p - 1]; bj[p] = bj[p - 1]; p--;
                }
                bd[p] = dm; bj[p] = j;
            }
        }
        const float DT = (float)(4.05 / 4.2);
#pragma unroll
        for (int k = 0; k < KNB; k++) {
            float d = bd[k]; int j = bj[k];
            bool ev = (d < DT) && vi;
            float m = ev ? 1.0f : 0.0f;
            float dxf = cx[j] - cxi;          // dst - src (ref order)
            float dyf = cy[j] - cyi;
            float sx = dxf * dxf;
            float sy = dyf * dyf;
            float s2 = sx + sy;
            float cd = (s2 > 0.0f) ? sqrtf(s2) : 0.0f;
            int e = b * (MAXN * KNB) + i * KNB + k;
            o_src[e] = ev ? (float)(i + b * MAXN) : 0.0f;
            o_dst[e] = ev ? (float)(j + b * MAXN) : 0.0f;
            o_ef[3 * e + 0] = dxf * m;
            o_ef[3 * e + 1] = dyf * m;
            o_ef[3 * e + 2] = cd * m;
            o_ev[e] = m;
        }
    }
}

extern "C" void kernel_launch(void* const* d_in, const int* in_sizes, int n_in,
                              void* d_out, int out_size, void* d_ws, size_t ws_size,
                              hipStream_t stream) {
    const float* img = (const float*)d_in[0];
    const float* w1  = (const float*)d_in[1];
    const float* w2  = (const float*)d_in[2];
    const float* w3  = (const float*)d_in[3];

    float* resp = (float*)d_ws;                       // BATCH*FLAT floats
    float* topv = resp + (size_t)BATCH * FLAT;        // NTOT floats
    int*   topi = (int*)(topv + NTOT);                // NTOT ints
    float* out = (float*)d_out;

    k_crop_conv<<<BATCH, 256, 0, stream>>>(img, w1, w2, w3, resp);
    k_topk<<<BATCH, 256, 0, stream>>>(resp, topv, topi);
    k_edges<<<BATCH, 256, 0, stream>>>(resp, topv, topi, out);
}

// Round 3
// 559.049 us; speedup vs baseline: 1.4997x; 1.4997x over previous
//
#include <hip/hip_runtime.h>
#include <stdint.h>

#define BATCH 64
#define IMH 512
#define IMW 512
#define NCH 3
#define NPIX 4096            // 64*64
#define FLAT 12288           // 3*4096
#define MAXN 196
#define KNB 6
#define NTOT (BATCH*MAXN)    // 12544
#define ETOT (NTOT*KNB)      // 75264

// out layout (float32 words), flat concat in reference return order
#define OFF_NODES 0
#define OFF_SRC   62720
#define OFF_DST   137984
#define OFF_EF    213248
#define OFF_BI    439040
#define OFF_NV    451584
#define OFF_EV    464128

// ---------------- kernel 1: crop (bilinear, fp32 exact) + gray + 3 DoG convs ----
__global__ void k_crop_conv(const float* __restrict__ img,
                            const float* __restrict__ w1,
                            const float* __restrict__ w2,
                            const float* __restrict__ w3,
                            float* __restrict__ resp)
{
#pragma clang fp contract(off)
    int b = blockIdx.x;
    int tid = threadIdx.x;
    __shared__ float gray[64][64];
    __shared__ float wk1[9], wk2[25], wk3[81];
    if (tid < 9)  wk1[tid] = w1[tid];
    if (tid < 25) wk2[tid] = w2[tid];
    if (tid < 81) wk3[tid] = w3[tid];
    __syncthreads();

    const float* ib = img + (size_t)b * NCH * IMH * IMW;
    for (int p = tid; p < NPIX; p += blockDim.x) {
        int y = p >> 6, x = p & 63;
        float bx = ((float)x + 0.5f) / 32.0f - 1.0f;
        float gx = bx * 0.03125f;
        float px = (gx + 1.0f) * 512.0f / 2.0f - 0.5f;
        float by = ((float)y + 0.5f) / 32.0f - 1.0f;
        float gy = by * 0.03125f;
        float py = (gy + 1.0f) * 512.0f / 2.0f - 0.5f;
        int ix0 = (int)floorf(px); float fx = px - (float)ix0;
        int iy0 = (int)floorf(py); float fy = py - (float)iy0;
        // all sample points are interior (px in [247.6, 263.4]) -> v0=v1=1
        float wx0 = 1.0f - fx, wx1 = fx;
        float wy0 = 1.0f - fy, wy1 = fy;
        float s[3];
        for (int c = 0; c < 3; c++) {
            const float* cb = ib + (size_t)c * IMH * IMW;
            float a00 = cb[iy0 * IMW + ix0];
            float a01 = cb[iy0 * IMW + ix0 + 1];
            float a10 = cb[(iy0 + 1) * IMW + ix0];
            float a11 = cb[(iy0 + 1) * IMW + ix0 + 1];
            float t0 = a00 * wx0 + a01 * wx1;   // x-gather first (ref order)
            float t1 = a10 * wx0 + a11 * wx1;
            s[c] = t0 * wy0 + t1 * wy1;         // then y-gather
        }
        gray[y][x] = ((s[0] + s[1]) + s[2]) / 3.0f;   // mean over channels
    }
    __syncthreads();

    for (int p = tid; p < NPIX; p += blockDim.x) {
        int y = p >> 6, x = p & 63;
        double a1 = 0.0, a2 = 0.0, a3 = 0.0;
        for (int ky = 0; ky < 3; ky++) {
            int yy = y + ky - 1; if (yy < 0 || yy >= 64) continue;
            for (int kx = 0; kx < 3; kx++) {
                int xx = x + kx - 1; if (xx < 0 || xx >= 64) continue;
                a1 += (double)gray[yy][xx] * (double)wk1[ky * 3 + kx];
            }
        }
        for (int ky = 0; ky < 5; ky++) {
            int yy = y + ky - 2; if (yy < 0 || yy >= 64) continue;
            for (int kx = 0; kx < 5; kx++) {
                int xx = x + kx - 2; if (xx < 0 || xx >= 64) continue;
                a2 += (double)gray[yy][xx] * (double)wk2[ky * 5 + kx];
            }
        }
        for (int ky = 0; ky < 9; ky++) {
            int yy = y + ky - 4; if (yy < 0 || yy >= 64) continue;
            for (int kx = 0; kx < 9; kx++) {
                int xx = x + kx - 4; if (xx < 0 || xx >= 64) continue;
                a3 += (double)gray[yy][xx] * (double)wk3[ky * 9 + kx];
            }
        }
        size_t base = (size_t)b * FLAT;
        resp[base + p]            = (float)a1;
        resp[base + NPIX + p]     = (float)a2;
        resp[base + 2 * NPIX + p] = (float)a3;
    }
}

// ---------------- kernel 2: radix-select + bitonic top-196 (val desc, idx asc) --
#define NBIN 2048
#define SCAP 2048

__global__ void k_topk(const float* __restrict__ resp,
                       float* __restrict__ topv,
                       int* __restrict__ topi)
{
    int b = blockIdx.x;
    int tid = threadIdx.x;
    __shared__ uint32_t keys[FLAT];                 // 48 KiB
    __shared__ int hist[NBIN];                      // 8 KiB
    __shared__ int ps[256];
    __shared__ int red[256];
    __shared__ unsigned long long sb[SCAP];         // 16 KiB
    __shared__ int cnt;

    // 1) keys: float bits of |v| if |v| > 0.1 else 0 (monotone for positive floats)
    const float* rb = resp + (size_t)b * FLAT;
    for (int j = tid; j < NBIN; j += 256) hist[j] = 0;
    __syncthreads();
    for (int j = tid; j < FLAT; j += 256) {
        float v = rb[j];
        float m = fabsf(v);
        union { float f; uint32_t u; } cv; cv.f = m;
        uint32_t k = (m > 0.1f) ? cv.u : 0u;
        keys[j] = k;
        if (k) atomicAdd(&hist[k >> 20], 1);        // bits[30:20] -> 2048 bins
    }
    __syncthreads();

    // 2) suffix counts over 8-bin groups: ps[t] = #keys in bins >= t*8
    int part = 0;
#pragma unroll
    for (int q = 0; q < 8; q++) part += hist[tid * 8 + q];
    ps[tid] = part;
    __syncthreads();
    for (int off = 1; off < 256; off <<= 1) {
        int v = ps[tid] + ((tid + off < 256) ? ps[tid + off] : 0);
        __syncthreads();
        ps[tid] = v;
        __syncthreads();
    }
    // 3) find B = max bin with (#keys in bins >= B) >= MAXN ; 0 if total < MAXN
    int base = (tid == 255) ? 0 : ps[tid + 1];
    int best = -1;
    int acc = base;
    for (int q = 7; q >= 0; q--) {
        acc += hist[tid * 8 + q];
        if (acc >= MAXN) { best = tid * 8 + q; break; }   // largest such bin in range
    }
    red[tid] = best;
    __syncthreads();
    for (int off = 128; off >= 1; off >>= 1) {
        if (tid < off) { int o = red[tid + off]; if (o > red[tid]) red[tid] = o; }
        __syncthreads();
    }
    int B = red[0] > 0 ? red[0] : 0;
    if (tid == 0) cnt = 0;
    __syncthreads();

    // 4) collect candidates (bins >= B) as composite (key<<32)|(~idx)
    for (int j = tid; j < FLAT; j += 256) {
        uint32_t k = keys[j];
        if (k && (int)(k >> 20) >= B) {
            int p = atomicAdd(&cnt, 1);
            if (p < SCAP)
                sb[p] = ((unsigned long long)k << 32) | (unsigned long long)(0xFFFFFFFFu - (uint32_t)j);
        }
    }
    __syncthreads();
    int n = cnt; if (n > SCAP) n = SCAP;
    for (int i = tid; i < SCAP; i += 256) if (i >= n) sb[i] = 0ULL;
    __syncthreads();

    // 5) bitonic sort descending over SCAP entries
    for (unsigned k = 2; k <= SCAP; k <<= 1) {
        for (unsigned j = k >> 1; j > 0; j >>= 1) {
            for (unsigned i = tid; i < SCAP; i += 256) {
                unsigned l = i ^ j;
                if (l > i) {
                    unsigned long long a = sb[i], c = sb[l];
                    bool up = ((i & k) == 0);          // descending blocks
                    if ((up && a < c) || (!up && a > c)) { sb[i] = c; sb[l] = a; }
                }
            }
            __syncthreads();
        }
    }

    // 6) emit first 196
    if (tid < MAXN) {
        unsigned long long e = sb[tid];
        uint32_t kh = (uint32_t)(e >> 32);
        if (kh) {
            union { uint32_t u; float f; } cv; cv.u = kh;
            topv[b * MAXN + tid] = cv.f;
            topi[b * MAXN + tid] = (int)(0xFFFFFFFFu - (uint32_t)(e & 0xFFFFFFFFu));
        } else {
            topv[b * MAXN + tid] = -1.0f;
            topi[b * MAXN + tid] = 0;
        }
    }
}

// ---------------- kernel 3: nodes + 6-NN + edges, one block per batch ----------
__global__ void k_edges(const float* __restrict__ resp,
                        const float* __restrict__ topv,
                        const int* __restrict__ topi,
                        float* __restrict__ out)
{
#pragma clang fp contract(off)
    int b = blockIdx.x;
    int tid = threadIdx.x;
    __shared__ float cx[MAXN], cy[MAXN];
    __shared__ int   vld[MAXN];

    float* o_nodes = out + OFF_NODES;
    float* o_src   = out + OFF_SRC;
    float* o_dst   = out + OFF_DST;
    float* o_ef    = out + OFF_EF;
    float* o_bi    = out + OFF_BI;
    float* o_nv    = out + OFF_NV;
    float* o_ev    = out + OFF_EV;

    if (tid < MAXN) {
        float v  = topv[b * MAXN + tid];
        int   idx = topi[b * MAXN + tid];
        bool  val = v > 0.1f;
        int c   = idx >> 12;
        int rem = idx & 4095;
        int yi  = rem >> 6;
        int xi  = rem & 63;
        float xc = (float)xi / 63.0f * 2.0f - 1.0f;
        float yc = (float)yi / 63.0f * 2.0f - 1.0f;
        float x2 = xc * xc, y2 = yc * yc;
        float ecc = sqrtf(x2 + y2);
        float rvv = resp[(size_t)b * FLAT + idx];
        float pol = (rvv > 0.0f) ? 1.0f : ((rvv < 0.0f) ? -1.0f : 0.0f);
        float m = val ? 1.0f : 0.0f;
        size_t n = (size_t)b * MAXN + tid;
        o_nodes[n * 5 + 0] = xc * m;
        o_nodes[n * 5 + 1] = yc * m;
        o_nodes[n * 5 + 2] = pol * m;
        o_nodes[n * 5 + 3] = (float)c * m;
        o_nodes[n * 5 + 4] = ecc * m;
        o_nv[n] = m;
        o_bi[n] = (float)b;
        cx[tid] = xc * m;   // coords taken AFTER validity zeroing (ref semantics)
        cy[tid] = yc * m;
        vld[tid] = val ? 1 : 0;
    }
    __syncthreads();

    if (tid < MAXN) {
        int i = tid;
        float bd[KNB]; int bj[KNB];
#pragma unroll
        for (int k = 0; k < KNB; k++) { bd[k] = 3.0e38f; bj[k] = 0; }
        float cxi = cx[i], cyi = cy[i];
        int vi = vld[i];
        for (int j = 0; j < MAXN; j++) {
            float dx = cxi - cx[j];
            float dy = cyi - cy[j];
            float sx = dx * dx;
            float sy = dy * dy;
            float d2 = sx + sy;
            float dist = (d2 > 0.0f) ? sqrtf(d2) : 0.0f;
            bool ok = vi && vld[j] && (i != j);
            float dm = ok ? dist : 1.0e9f;
            if (dm < bd[KNB - 1]) {           // strict: equal dist keeps earlier j
                int p = KNB - 1;
                while (p > 0 && dm < bd[p - 1]) {
                    bd[p] = bd[p - 1]; bj[p] = bj[p - 1]; p--;
                }
                bd[p] = dm; bj[p] = j;
            }
        }
        const float DT = (float)(4.05 / 4.2);
#pragma unroll
        for (int k = 0; k < KNB; k++) {
            float d = bd[k]; int j = bj[k];
            bool ev = (d < DT) && vi;
            float m = ev ? 1.0f : 0.0f;
            float dxf = cx[j] - cxi;          // dst - src (ref order)
            float dyf = cy[j] - cyi;
            float sx = dxf * dxf;
            float sy = dyf * dyf;
            float s2 = sx + sy;
            float cd = (s2 > 0.0f) ? sqrtf(s2) : 0.0f;
            int e = b * (MAXN * KNB) + i * KNB + k;
            o_src[e] = ev ? (float)(i + b * MAXN) : 0.0f;
            o_dst[e] = ev ? (float)(j + b * MAXN) : 0.0f;
            o_ef[3 * e + 0] = dxf * m;
            o_ef[3 * e + 1] = dyf * m;
            o_ef[3 * e + 2] = cd * m;
            o_ev[e] = m;
        }
    }
}

extern "C" void kernel_launch(void* const* d_in, const int* in_sizes, int n_in,
                              void* d_out, int out_size, void* d_ws, size_t ws_size,
                              hipStream_t stream) {
    const float* img = (const float*)d_in[0];
    const float* w1  = (const float*)d_in[1];
    const float* w2  = (const float*)d_in[2];
    const float* w3  = (const float*)d_in[3];

    float* resp = (float*)d_ws;                       // BATCH*FLAT floats
    float* topv = resp + (size_t)BATCH * FLAT;        // NTOT floats
    int*   topi = (int*)(topv + NTOT);                // NTOT ints
    float* out = (float*)d_out;

    k_crop_conv<<<BATCH, 256, 0, stream>>>(img, w1, w2, w3, resp);
    k_topk<<<BATCH, 256, 0, stream>>>(resp, topv, topi);
    k_edges<<<BATCH, 256, 0, stream>>>(resp, topv, topi, out);
}

// Round 4
// 393.214 us; speedup vs baseline: 2.1323x; 1.4217x over previous
//
#include <hip/hip_runtime.h>
#include <stdint.h>

#define BATCH 64
#define IMH 512
#define IMW 512
#define NCH 3
#define NPIX 4096            // 64*64
#define FLAT 12288           // 3*4096
#define MAXN 196
#define KNB 6
#define NTOT (BATCH*MAXN)    // 12544
#define ETOT (NTOT*KNB)      // 75264

// out layout (float32 words), flat concat in reference return order
#define OFF_NODES 0
#define OFF_SRC   62720
#define OFF_DST   137984
#define OFF_EF    213248
#define OFF_BI    439040
#define OFF_NV    451584
#define OFF_EV    464128

// ---------------- kernel 1: crop (bilinear, fp32 exact) + gray + 3 DoG convs ----
// grid = BATCH*16 blocks; block (b, slice) computes output rows rs..rs+3 of image b.
// LDS gray holds rows rs-4 .. rs+7 (12 rows) — the 9x9 halo for this slice.
__global__ void k_crop_conv(const float* __restrict__ img,
                            const float* __restrict__ w1,
                            const float* __restrict__ w2,
                            const float* __restrict__ w3,
                            float* __restrict__ resp)
{
#pragma clang fp contract(off)
    int blk = blockIdx.x;
    int b   = blk >> 4;
    int rs  = (blk & 15) << 2;          // first output row of this slice
    int tid = threadIdx.x;
    __shared__ float gray[12][64];
    __shared__ float wk1[9], wk2[25], wk3[81];
    if (tid < 9)  wk1[tid] = w1[tid];
    if (tid < 25) wk2[tid] = w2[tid];
    if (tid < 81) wk3[tid] = w3[tid];

    const float* ib = img + (size_t)b * NCH * IMH * IMW;
    for (int s = tid; s < 768; s += 256) {          // 12 rows x 64 cols
        int r = s >> 6, x = s & 63;
        int y = rs - 4 + r;
        if (y >= 0 && y < 64) {
            // identical fp32 op order to the reference _crop64
            float bx = ((float)x + 0.5f) / 32.0f - 1.0f;
            float gx = bx * 0.03125f;
            float px = (gx + 1.0f) * 512.0f / 2.0f - 0.5f;
            float by = ((float)y + 0.5f) / 32.0f - 1.0f;
            float gy = by * 0.03125f;
            float py = (gy + 1.0f) * 512.0f / 2.0f - 0.5f;
            int ix0 = (int)floorf(px); float fx = px - (float)ix0;
            int iy0 = (int)floorf(py); float fy = py - (float)iy0;
            // all sample points are interior (px in [247.6, 263.4]) -> v0=v1=1
            float wx0 = 1.0f - fx, wx1 = fx;
            float wy0 = 1.0f - fy, wy1 = fy;
            float sc[3];
            for (int c = 0; c < 3; c++) {
                const float* cb = ib + (size_t)c * IMH * IMW;
                float a00 = cb[iy0 * IMW + ix0];
                float a01 = cb[iy0 * IMW + ix0 + 1];
                float a10 = cb[(iy0 + 1) * IMW + ix0];
                float a11 = cb[(iy0 + 1) * IMW + ix0 + 1];
                float t0 = a00 * wx0 + a01 * wx1;   // x-gather first (ref order)
                float t1 = a10 * wx0 + a11 * wx1;
                sc[c] = t0 * wy0 + t1 * wy1;        // then y-gather
            }
            gray[r][x] = ((sc[0] + sc[1]) + sc[2]) / 3.0f;
        }
    }
    __syncthreads();

    // one conv output pixel per thread
    int ly = tid >> 6;                  // 0..3
    int y  = rs + ly;
    int x  = tid & 63;
    double a1 = 0.0, a2 = 0.0, a3 = 0.0;
#pragma unroll
    for (int ky = 0; ky < 3; ky++) {
        int yy = y + ky - 1;
        bool yok = (yy >= 0) & (yy < 64);
        int lr = ly + ky + 3;           // (yy - (rs-4))
#pragma unroll
        for (int kx = 0; kx < 3; kx++) {
            int xx = x + kx - 1;
            if (yok && xx >= 0 && xx < 64)
                a1 += (double)gray[lr][xx] * (double)wk1[ky * 3 + kx];
        }
    }
#pragma unroll
    for (int ky = 0; ky < 5; ky++) {
        int yy = y + ky - 2;
        bool yok = (yy >= 0) & (yy < 64);
        int lr = ly + ky + 2;
#pragma unroll
        for (int kx = 0; kx < 5; kx++) {
            int xx = x + kx - 2;
            if (yok && xx >= 0 && xx < 64)
                a2 += (double)gray[lr][xx] * (double)wk2[ky * 5 + kx];
        }
    }
#pragma unroll
    for (int ky = 0; ky < 9; ky++) {
        int yy = y + ky - 4;
        bool yok = (yy >= 0) & (yy < 64);
        int lr = ly + ky;
#pragma unroll
        for (int kx = 0; kx < 9; kx++) {
            int xx = x + kx - 4;
            if (yok && xx >= 0 && xx < 64)
                a3 += (double)gray[lr][xx] * (double)wk3[ky * 9 + kx];
        }
    }
    size_t base = (size_t)b * FLAT;
    int p = (y << 6) | x;
    resp[base + p]            = (float)a1;
    resp[base + NPIX + p]     = (float)a2;
    resp[base + 2 * NPIX + p] = (float)a3;
}

// ---------------- kernel 2: radix-select + bitonic top-196 (val desc, idx asc) --
#define NBIN 2048
#define SCAP 2048

__global__ void k_topk(const float* __restrict__ resp,
                       float* __restrict__ topv,
                       int* __restrict__ topi)
{
    int b = blockIdx.x;
    int tid = threadIdx.x;
    __shared__ uint32_t keys[FLAT];                 // 48 KiB
    __shared__ int hist[NBIN];                      // 8 KiB
    __shared__ int ps[256];
    __shared__ int red[256];
    __shared__ unsigned long long sb[SCAP];         // 16 KiB
    __shared__ int cnt;

    // 1) keys: float bits of |v| if |v| > 0.1 else 0 (monotone for positive floats)
    const float* rb = resp + (size_t)b * FLAT;
    for (int j = tid; j < NBIN; j += 256) hist[j] = 0;
    __syncthreads();
    for (int j = tid; j < FLAT; j += 256) {
        float v = rb[j];
        float m = fabsf(v);
        union { float f; uint32_t u; } cv; cv.f = m;
        uint32_t k = (m > 0.1f) ? cv.u : 0u;
        keys[j] = k;
        if (k) atomicAdd(&hist[k >> 20], 1);        // bits[30:20] -> 2048 bins
    }
    __syncthreads();

    // 2) suffix counts over 8-bin groups: ps[t] = #keys in bins >= t*8
    int part = 0;
#pragma unroll
    for (int q = 0; q < 8; q++) part += hist[tid * 8 + q];
    ps[tid] = part;
    __syncthreads();
    for (int off = 1; off < 256; off <<= 1) {
        int v = ps[tid] + ((tid + off < 256) ? ps[tid + off] : 0);
        __syncthreads();
        ps[tid] = v;
        __syncthreads();
    }
    // 3) find B = max bin with (#keys in bins >= B) >= MAXN ; 0 if total < MAXN
    int base = (tid == 255) ? 0 : ps[tid + 1];
    int best = -1;
    int acc = base;
    for (int q = 7; q >= 0; q--) {
        acc += hist[tid * 8 + q];
        if (acc >= MAXN) { best = tid * 8 + q; break; }   // largest such bin in range
    }
    red[tid] = best;
    __syncthreads();
    for (int off = 128; off >= 1; off >>= 1) {
        if (tid < off) { int o = red[tid + off]; if (o > red[tid]) red[tid] = o; }
        __syncthreads();
    }
    int B = red[0] > 0 ? red[0] : 0;
    if (tid == 0) cnt = 0;
    __syncthreads();

    // 4) collect candidates (bins >= B) as composite (key<<32)|(~idx)
    for (int j = tid; j < FLAT; j += 256) {
        uint32_t k = keys[j];
        if (k && (int)(k >> 20) >= B) {
            int p = atomicAdd(&cnt, 1);
            if (p < SCAP)
                sb[p] = ((unsigned long long)k << 32) | (unsigned long long)(0xFFFFFFFFu - (uint32_t)j);
        }
    }
    __syncthreads();
    int n = cnt; if (n > SCAP) n = SCAP;
    for (int i = tid; i < SCAP; i += 256) if (i >= n) sb[i] = 0ULL;
    __syncthreads();

    // 5) bitonic sort descending over SCAP entries
    for (unsigned k = 2; k <= SCAP; k <<= 1) {
        for (unsigned j = k >> 1; j > 0; j >>= 1) {
            for (unsigned i = tid; i < SCAP; i += 256) {
                unsigned l = i ^ j;
                if (l > i) {
                    unsigned long long a = sb[i], c = sb[l];
                    bool up = ((i & k) == 0);          // descending blocks
                    if ((up && a < c) || (!up && a > c)) { sb[i] = c; sb[l] = a; }
                }
            }
            __syncthreads();
        }
    }

    // 6) emit first 196
    if (tid < MAXN) {
        unsigned long long e = sb[tid];
        uint32_t kh = (uint32_t)(e >> 32);
        if (kh) {
            union { uint32_t u; float f; } cv; cv.u = kh;
            topv[b * MAXN + tid] = cv.f;
            topi[b * MAXN + tid] = (int)(0xFFFFFFFFu - (uint32_t)(e & 0xFFFFFFFFu));
        } else {
            topv[b * MAXN + tid] = -1.0f;
            topi[b * MAXN + tid] = 0;
        }
    }
}

// ---------------- kernel 3: nodes + 6-NN + edges, one block per batch ----------
__global__ void k_edges(const float* __restrict__ resp,
                        const float* __restrict__ topv,
                        const int* __restrict__ topi,
                        float* __restrict__ out)
{
#pragma clang fp contract(off)
    int b = blockIdx.x;
    int tid = threadIdx.x;
    __shared__ float cx[MAXN], cy[MAXN];
    __shared__ int   vld[MAXN];

    float* o_nodes = out + OFF_NODES;
    float* o_src   = out + OFF_SRC;
    float* o_dst   = out + OFF_DST;
    float* o_ef    = out + OFF_EF;
    float* o_bi    = out + OFF_BI;
    float* o_nv    = out + OFF_NV;
    float* o_ev    = out + OFF_EV;

    if (tid < MAXN) {
        float v  = topv[b * MAXN + tid];
        int   idx = topi[b * MAXN + tid];
        bool  val = v > 0.1f;
        int c   = idx >> 12;
        int rem = idx & 4095;
        int yi  = rem >> 6;
        int xi  = rem & 63;
        float xc = (float)xi / 63.0f * 2.0f - 1.0f;
        float yc = (float)yi / 63.0f * 2.0f - 1.0f;
        float x2 = xc * xc, y2 = yc * yc;
        float ecc = sqrtf(x2 + y2);
        float rvv = resp[(size_t)b * FLAT + idx];
        float pol = (rvv > 0.0f) ? 1.0f : ((rvv < 0.0f) ? -1.0f : 0.0f);
        float m = val ? 1.0f : 0.0f;
        size_t n = (size_t)b * MAXN + tid;
        o_nodes[n * 5 + 0] = xc * m;
        o_nodes[n * 5 + 1] = yc * m;
        o_nodes[n * 5 + 2] = pol * m;
        o_nodes[n * 5 + 3] = (float)c * m;
        o_nodes[n * 5 + 4] = ecc * m;
        o_nv[n] = m;
        o_bi[n] = (float)b;
        cx[tid] = xc * m;   // coords taken AFTER validity zeroing (ref semantics)
        cy[tid] = yc * m;
        vld[tid] = val ? 1 : 0;
    }
    __syncthreads();

    if (tid < MAXN) {
        int i = tid;
        float bd[KNB]; int bj[KNB];
#pragma unroll
        for (int k = 0; k < KNB; k++) { bd[k] = 3.0e38f; bj[k] = 0; }
        float cxi = cx[i], cyi = cy[i];
        int vi = vld[i];
        for (int j = 0; j < MAXN; j++) {
            float dx = cxi - cx[j];
            float dy = cyi - cy[j];
            float sx = dx * dx;
            float sy = dy * dy;
            float d2 = sx + sy;
            float dist = (d2 > 0.0f) ? sqrtf(d2) : 0.0f;
            bool ok = vi && vld[j] && (i != j);
            float dm = ok ? dist : 1.0e9f;
            if (dm < bd[KNB - 1]) {           // strict: equal dist keeps earlier j
                int p = KNB - 1;
                while (p > 0 && dm < bd[p - 1]) {
                    bd[p] = bd[p - 1]; bj[p] = bj[p - 1]; p--;
                }
                bd[p] = dm; bj[p] = j;
            }
        }
        const float DT = (float)(4.05 / 4.2);
#pragma unroll
        for (int k = 0; k < KNB; k++) {
            float d = bd[k]; int j = bj[k];
            bool ev = (d < DT) && vi;
            float m = ev ? 1.0f : 0.0f;
            float dxf = cx[j] - cxi;          // dst - src (ref order)
            float dyf = cy[j] - cyi;
            float sx = dxf * dxf;
            float sy = dyf * dyf;
            float s2 = sx + sy;
            float cd = (s2 > 0.0f) ? sqrtf(s2) : 0.0f;
            int e = b * (MAXN * KNB) + i * KNB + k;
            o_src[e] = ev ? (float)(i + b * MAXN) : 0.0f;
            o_dst[e] = ev ? (float)(j + b * MAXN) : 0.0f;
            o_ef[3 * e + 0] = dxf * m;
            o_ef[3 * e + 1] = dyf * m;
            o_ef[3 * e + 2] = cd * m;
            o_ev[e] = m;
        }
    }
}

extern "C" void kernel_launch(void* const* d_in, const int* in_sizes, int n_in,
                              void* d_out, int out_size, void* d_ws, size_t ws_size,
                              hipStream_t stream) {
    const float* img = (const float*)d_in[0];
    const float* w1  = (const float*)d_in[1];
    const float* w2  = (const float*)d_in[2];
    const float* w3  = (const float*)d_in[3];

    float* resp = (float*)d_ws;                       // BATCH*FLAT floats
    float* topv = resp + (size_t)BATCH * FLAT;        // NTOT floats
    int*   topi = (int*)(topv + NTOT);                // NTOT ints
    float* out = (float*)d_out;

    k_crop_conv<<<BATCH * 16, 256, 0, stream>>>(img, w1, w2, w3, resp);
    k_topk<<<BATCH, 256, 0, stream>>>(resp, topv, topi);
    k_edges<<<BATCH, 256, 0, stream>>>(resp, topv, topi, out);
}

// Round 5
// 335.873 us; speedup vs baseline: 2.4963x; 1.1707x over previous
//
#include <hip/hip_runtime.h>
#include <stdint.h>

#define BATCH 64
#define IMH 512
#define IMW 512
#define NCH 3
#define NPIX 4096            // 64*64
#define FLAT 12288           // 3*4096
#define MAXN 196
#define KNB 6
#define NTOT (BATCH*MAXN)    // 12544
#define ETOT (NTOT*KNB)      // 75264

// out layout (float32 words), flat concat in reference return order
#define OFF_NODES 0
#define OFF_SRC   62720
#define OFF_DST   137984
#define OFF_EF    213248
#define OFF_BI    439040
#define OFF_NV    451584
#define OFF_EV    464128

// ---------------- kernel 1: crop (bilinear, fp32 exact) + gray + 3 DoG convs ----
// grid = BATCH*16 blocks; block (b, slice) computes output rows rs..rs+3 of image b.
__global__ void k_crop_conv(const float* __restrict__ img,
                            const float* __restrict__ w1,
                            const float* __restrict__ w2,
                            const float* __restrict__ w3,
                            float* __restrict__ resp)
{
#pragma clang fp contract(off)
    int blk = blockIdx.x;
    int b   = blk >> 4;
    int rs  = (blk & 15) << 2;          // first output row of this slice
    int tid = threadIdx.x;
    __shared__ float gray[12][64];
    __shared__ float wk1[9], wk2[25], wk3[81];
    if (tid < 9)  wk1[tid] = w1[tid];
    if (tid < 25) wk2[tid] = w2[tid];
    if (tid < 81) wk3[tid] = w3[tid];

    const float* ib = img + (size_t)b * NCH * IMH * IMW;
    for (int s = tid; s < 768; s += 256) {          // 12 rows x 64 cols
        int r = s >> 6, x = s & 63;
        int y = rs - 4 + r;
        if (y >= 0 && y < 64) {
            // identical fp32 op order to the reference _crop64
            float bx = ((float)x + 0.5f) / 32.0f - 1.0f;
            float gx = bx * 0.03125f;
            float px = (gx + 1.0f) * 512.0f / 2.0f - 0.5f;
            float by = ((float)y + 0.5f) / 32.0f - 1.0f;
            float gy = by * 0.03125f;
            float py = (gy + 1.0f) * 512.0f / 2.0f - 0.5f;
            int ix0 = (int)floorf(px); float fx = px - (float)ix0;
            int iy0 = (int)floorf(py); float fy = py - (float)iy0;
            // all sample points are interior -> v0=v1=1
            float wx0 = 1.0f - fx, wx1 = fx;
            float wy0 = 1.0f - fy, wy1 = fy;
            float sc[3];
            for (int c = 0; c < 3; c++) {
                const float* cb = ib + (size_t)c * IMH * IMW;
                float a00 = cb[iy0 * IMW + ix0];
                float a01 = cb[iy0 * IMW + ix0 + 1];
                float a10 = cb[(iy0 + 1) * IMW + ix0];
                float a11 = cb[(iy0 + 1) * IMW + ix0 + 1];
                float t0 = a00 * wx0 + a01 * wx1;   // x-gather first (ref order)
                float t1 = a10 * wx0 + a11 * wx1;
                sc[c] = t0 * wy0 + t1 * wy1;        // then y-gather
            }
            gray[r][x] = ((sc[0] + sc[1]) + sc[2]) / 3.0f;
        }
    }
    __syncthreads();

    // one conv output pixel per thread
    int ly = tid >> 6;                  // 0..3
    int y  = rs + ly;
    int x  = tid & 63;
    double a1 = 0.0, a2 = 0.0, a3 = 0.0;
#pragma unroll
    for (int ky = 0; ky < 3; ky++) {
        int yy = y + ky - 1;
        bool yok = (yy >= 0) & (yy < 64);
        int lr = ly + ky + 3;
#pragma unroll
        for (int kx = 0; kx < 3; kx++) {
            int xx = x + kx - 1;
            if (yok && xx >= 0 && xx < 64)
                a1 += (double)gray[lr][xx] * (double)wk1[ky * 3 + kx];
        }
    }
#pragma unroll
    for (int ky = 0; ky < 5; ky++) {
        int yy = y + ky - 2;
        bool yok = (yy >= 0) & (yy < 64);
        int lr = ly + ky + 2;
#pragma unroll
        for (int kx = 0; kx < 5; kx++) {
            int xx = x + kx - 2;
            if (yok && xx >= 0 && xx < 64)
                a2 += (double)gray[lr][xx] * (double)wk2[ky * 5 + kx];
        }
    }
#pragma unroll
    for (int ky = 0; ky < 9; ky++) {
        int yy = y + ky - 4;
        bool yok = (yy >= 0) & (yy < 64);
        int lr = ly + ky;
#pragma unroll
        for (int kx = 0; kx < 9; kx++) {
            int xx = x + kx - 4;
            if (yok && xx >= 0 && xx < 64)
                a3 += (double)gray[lr][xx] * (double)wk3[ky * 9 + kx];
        }
    }
    size_t base = (size_t)b * FLAT;
    int p = (y << 6) | x;
    resp[base + p]            = (float)a1;
    resp[base + NPIX + p]     = (float)a2;
    resp[base + 2 * NPIX + p] = (float)a3;
}

// ---------------- kernel 2: fused top-196 (radix-select + rank-scatter) + nodes
//                  + 6-NN + edge outputs. One block per batch image. -------------
#define NBIN 2048
#define SCAP 2048

__global__ void k_graph(const float* __restrict__ resp,
                        float* __restrict__ out)
{
#pragma clang fp contract(off)
    int b = blockIdx.x;
    int tid = threadIdx.x;
    __shared__ uint32_t keys[FLAT];                 // 48 KiB
    __shared__ int hist[NBIN];                      // 8 KiB
    __shared__ int ps[256];
    __shared__ int red[256];
    __shared__ unsigned long long sb[SCAP];         // 16 KiB
    __shared__ float cx[MAXN], cy[MAXN];
    __shared__ int   vld[MAXN];
    __shared__ int cnt;

    float* o_nodes = out + OFF_NODES;
    float* o_src   = out + OFF_SRC;
    float* o_dst   = out + OFF_DST;
    float* o_ef    = out + OFF_EF;
    float* o_bi    = out + OFF_BI;
    float* o_nv    = out + OFF_NV;
    float* o_ev    = out + OFF_EV;

    // 1) keys: float bits of |v| if |v| > 0.1 else 0 (monotone for positive floats)
    const float* rb = resp + (size_t)b * FLAT;
    for (int j = tid; j < NBIN; j += 256) hist[j] = 0;
    if (tid == 0) cnt = 0;
    __syncthreads();
    for (int j = tid; j < FLAT; j += 256) {
        float v = rb[j];
        float m = fabsf(v);
        union { float f; uint32_t u; } cv; cv.f = m;
        uint32_t k = (m > 0.1f) ? cv.u : 0u;
        keys[j] = k;
        if (k) atomicAdd(&hist[k >> 20], 1);        // bits[30:20] -> 2048 bins
    }
    __syncthreads();

    // 2) suffix counts over 8-bin groups: ps[t] = #keys in bins >= t*8
    int part = 0;
#pragma unroll
    for (int q = 0; q < 8; q++) part += hist[tid * 8 + q];
    ps[tid] = part;
    __syncthreads();
    for (int off = 1; off < 256; off <<= 1) {
        int v = ps[tid] + ((tid + off < 256) ? ps[tid + off] : 0);
        __syncthreads();
        ps[tid] = v;
        __syncthreads();
    }
    // 3) find B = max bin with (#keys in bins >= B) >= MAXN ; 0 if total < MAXN
    int base = (tid == 255) ? 0 : ps[tid + 1];
    int best = -1;
    int acc = base;
    for (int q = 7; q >= 0; q--) {
        acc += hist[tid * 8 + q];
        if (acc >= MAXN) { best = tid * 8 + q; break; }
    }
    red[tid] = best;
    __syncthreads();
    for (int off = 128; off >= 1; off >>= 1) {
        if (tid < off) { int o = red[tid + off]; if (o > red[tid]) red[tid] = o; }
        __syncthreads();
    }
    int B = red[0] > 0 ? red[0] : 0;
    __syncthreads();

    // 4) collect candidates (bins >= B) as composite (key<<32)|(~idx)
    //    descending composite order == (value desc, idx asc) == lax.top_k order
    for (int j = tid; j < FLAT; j += 256) {
        uint32_t k = keys[j];
        if (k && (int)(k >> 20) >= B) {
            int p = atomicAdd(&cnt, 1);
            if (p < SCAP)
                sb[p] = ((unsigned long long)k << 32) | (unsigned long long)(0xFFFFFFFFu - (uint32_t)j);
        }
    }
    __syncthreads();
    int n = cnt; if (n > SCAP) n = SCAP;
    int nv = n < MAXN ? n : MAXN;       // number of valid node slots

    // 5) rank-selection scatter: rank = #(strictly greater composites); ranks are
    //    a permutation of [0,n) (keys distinct via idx part). Slot = rank.
    for (int e = tid; e < n; e += 256) {
        unsigned long long key = sb[e];
        int rank = 0;
        for (int j = 0; j < n; j++) rank += (sb[j] > key) ? 1 : 0;
        if (rank < MAXN) {
            int idx = (int)(0xFFFFFFFFu - (uint32_t)(key & 0xFFFFFFFFu));
            int c   = idx >> 12;
            int rem = idx & 4095;
            int yi  = rem >> 6;
            int xi  = rem & 63;
            float xc = (float)xi / 63.0f * 2.0f - 1.0f;
            float yc = (float)yi / 63.0f * 2.0f - 1.0f;
            float x2 = xc * xc, y2 = yc * yc;
            float ecc = sqrtf(x2 + y2);
            float rvv = rb[idx];
            float pol = (rvv > 0.0f) ? 1.0f : ((rvv < 0.0f) ? -1.0f : 0.0f);
            size_t nn = (size_t)b * MAXN + rank;
            o_nodes[nn * 5 + 0] = xc;       // valid slot: mask m == 1
            o_nodes[nn * 5 + 1] = yc;
            o_nodes[nn * 5 + 2] = pol;
            o_nodes[nn * 5 + 3] = (float)c;
            o_nodes[nn * 5 + 4] = ecc;
            o_nv[nn] = 1.0f;
            cx[rank] = xc;
            cy[rank] = yc;
            vld[rank] = 1;
        }
    }
    // invalid slots [nv, 196): zero nodes, coords 0 (|±0| identical downstream)
    if (tid >= nv && tid < MAXN) {
        size_t nn = (size_t)b * MAXN + tid;
        o_nodes[nn * 5 + 0] = 0.0f;
        o_nodes[nn * 5 + 1] = 0.0f;
        o_nodes[nn * 5 + 2] = 0.0f;
        o_nodes[nn * 5 + 3] = 0.0f;
        o_nodes[nn * 5 + 4] = 0.0f;
        o_nv[nn] = 0.0f;
        cx[tid] = 0.0f;
        cy[tid] = 0.0f;
        vld[tid] = 0;
    }
    if (tid < MAXN) o_bi[(size_t)b * MAXN + tid] = (float)b;
    __syncthreads();

    // 6) 6-NN + edge outputs (numerics identical to verified k_edges)
    if (tid < MAXN) {
        int i = tid;
        float bd[KNB]; int bj[KNB];
#pragma unroll
        for (int k = 0; k < KNB; k++) { bd[k] = 3.0e38f; bj[k] = 0; }
        float cxi = cx[i], cyi = cy[i];
        int vi = vld[i];
        for (int j = 0; j < MAXN; j++) {
            float dx = cxi - cx[j];
            float dy = cyi - cy[j];
            float sx = dx * dx;
            float sy = dy * dy;
            float d2 = sx + sy;
            float dist = (d2 > 0.0f) ? sqrtf(d2) : 0.0f;
            bool ok = vi && vld[j] && (i != j);
            float dm = ok ? dist : 1.0e9f;
            if (dm < bd[KNB - 1]) {           // strict: equal dist keeps earlier j
                int p = KNB - 1;
                while (p > 0 && dm < bd[p - 1]) {
                    bd[p] = bd[p - 1]; bj[p] = bj[p - 1]; p--;
                }
                bd[p] = dm; bj[p] = j;
            }
        }
        const float DT = (float)(4.05 / 4.2);
#pragma unroll
        for (int k = 0; k < KNB; k++) {
            float d = bd[k]; int j = bj[k];
            bool ev = (d < DT) && vi;
            float m = ev ? 1.0f : 0.0f;
            float dxf = cx[j] - cxi;          // dst - src (ref order)
            float dyf = cy[j] - cyi;
            float sx = dxf * dxf;
            float sy = dyf * dyf;
            float s2 = sx + sy;
            float cd = (s2 > 0.0f) ? sqrtf(s2) : 0.0f;
            int e = b * (MAXN * KNB) + i * KNB + k;
            o_src[e] = ev ? (float)(i + b * MAXN) : 0.0f;
            o_dst[e] = ev ? (float)(j + b * MAXN) : 0.0f;
            o_ef[3 * e + 0] = dxf * m;
            o_ef[3 * e + 1] = dyf * m;
            o_ef[3 * e + 2] = cd * m;
            o_ev[e] = m;
        }
    }
}

extern "C" void kernel_launch(void* const* d_in, const int* in_sizes, int n_in,
                              void* d_out, int out_size, void* d_ws, size_t ws_size,
                              hipStream_t stream) {
    const float* img = (const float*)d_in[0];
    const float* w1  = (const float*)d_in[1];
    const float* w2  = (const float*)d_in[2];
    const float* w3  = (const float*)d_in[3];

    float* resp = (float*)d_ws;                       // BATCH*FLAT floats
    float* out = (float*)d_out;

    k_crop_conv<<<BATCH * 16, 256, 0, stream>>>(img, w1, w2, w3, resp);
    k_graph<<<BATCH, 256, 0, stream>>>(resp, out);
}